// Round 25
// baseline (165.261 us; speedup 1.0000x reference)
//
#include <hip/hip_runtime.h>
#include <stdint.h>

#define NBATCH 16
#define NANCH  9
#define NHGT   128
#define NWID   256
#define NHW    (NHGT * NWID)       // 32768
#define NTOT   (NHW * NANCH)       // 294912
#define PRE    6000
#define POST   300
#define CAPN   8192
#define BINS   8192
#define BIN_SHIFT 19
#define NWORDS 94                  // ceil(6000/64)
#define RROWS  384                 // suppression-matrix rows+cols (exact fallback beyond)
#define SWORDS 6                   // stored words per row (columns < RROWS only)

// exact replacement for (div_rn(inter,uni) > 0.7f):  (double)inter >= (double)uni * M
#define MIDP 0x1.6666668p-1

__device__ __constant__ float c_AW[NANCH] = {184.f,368.f,736.f,128.f,256.f,512.f,88.f,176.f,352.f};
__device__ __constant__ float c_AH[NANCH] = {96.f,192.f,384.f,128.f,256.f,512.f,176.f,352.f,704.f};

__device__ __forceinline__ uint32_t f2key(float f) {
    uint32_t u = __float_as_uint(f);
    return (u & 0x80000000u) ? ~u : (u | 0x80000000u);
}

__device__ __forceinline__ bool iou_sup(const float4 bi, float areaI, const float4 bj, float areaJ) {
    float xx1 = fmaxf(bi.x, bj.x);
    float yy1 = fmaxf(bi.y, bj.y);
    float xx2 = fminf(bi.z, bj.z);
    float yy2 = fminf(bi.w, bj.w);
    float iw = fmaxf(__fadd_rn(__fsub_rn(xx2, xx1), 1.f), 0.f);
    float ih = fmaxf(__fadd_rn(__fsub_rn(yy2, yy1), 1.f), 0.f);
    float inter = __fmul_rn(iw, ih);
    float uni = __fsub_rn(__fadd_rn(areaI, areaJ), inter);
    return ((double)inter >= (double)uni * MIDP);
}

__device__ __forceinline__ bool decode_clip(float dx, float dy, float dw, float dh,
                                            float aw, float ah, float acx, float acy,
                                            float& x1, float& y1, float& x2, float& y2) {
    float pcx = __fadd_rn(__fmul_rn(dx, aw), acx);
    float pcy = __fadd_rn(__fmul_rn(dy, ah), acy);
    float pw  = __fmul_rn(expf(dw), aw);
    float ph  = __fmul_rn(expf(dh), ah);
    float hx  = __fmul_rn(0.5f, pw);
    float hy  = __fmul_rn(0.5f, ph);
    x1 = __fsub_rn(pcx, hx);
    y1 = __fsub_rn(pcy, hy);
    x2 = __fadd_rn(pcx, hx);
    y2 = __fadd_rn(pcy, hy);
    x1 = fminf(fmaxf(x1, 0.f), 4095.f);
    x2 = fminf(fmaxf(x2, 0.f), 4095.f);
    y1 = fminf(fmaxf(y1, 0.f), 2047.f);
    y2 = fminf(fmaxf(y2, 0.f), 2047.f);
    float wpl = __fadd_rn(__fsub_rn(x2, x1), 1.f);
    float hpl = __fadd_rn(__fsub_rn(y2, y1), 1.f);
    return (wpl >= 16.f) && (hpl >= 16.f);
}

// ---------------- K0: zero ghist ----------------
__global__ __launch_bounds__(256) void k_zero(uint4* __restrict__ ghist4) {
    ghist4[blockIdx.x * 256 + threadIdx.x] = make_uint4(0, 0, 0, 0);  // 128*256*16 = 524288 B
}

// ---------------- K1: LDS histogram (512 blocks, float4 loads) + key array ----------------
__global__ __launch_bounds__(256) void k_hist(const float* __restrict__ lab,
                                              const float* __restrict__ reg,
                                              uint32_t* __restrict__ ghist,
                                              uint32_t* __restrict__ keys) {
    __shared__ uint32_t hist[BINS];
    for (int i = threadIdx.x; i < BINS; i += 256) hist[i] = 0;
    __syncthreads();
    int b = blockIdx.x >> 5, sub = blockIdx.x & 31;
    int hw = (sub << 10) | (threadIdx.x << 2);
    int h = hw >> 8, w = hw & 255;
    const float* lb = lab + (size_t)b * 18 * NHW + hw;
    const float* rb = reg + (size_t)b * 36 * NHW + hw;
    uint32_t* kb = keys + (size_t)b * NANCH * NHW + hw;
    float acy  = (float)(h * 16) + 7.5f;
    float acx0 = (float)(w * 16) + 7.5f;
    float acx1 = acx0 + 16.0f;
    float acx2 = acx0 + 32.0f;
    float acx3 = acx0 + 48.0f;
#pragma unroll
    for (int a = 0; a < NANCH; ++a) {
        float4 s  = *(const float4*)&lb[(2 * a + 1) * NHW];
        float4 dx = *(const float4*)&rb[(4 * a + 0) * NHW];
        float4 dy = *(const float4*)&rb[(4 * a + 1) * NHW];
        float4 dwv = *(const float4*)&rb[(4 * a + 2) * NHW];
        float4 dhv = *(const float4*)&rb[(4 * a + 3) * NHW];
        float x1, y1, x2, y2;
        bool k0 = decode_clip(dx.x, dy.x, dwv.x, dhv.x, c_AW[a], c_AH[a], acx0, acy, x1, y1, x2, y2);
        bool k1 = decode_clip(dx.y, dy.y, dwv.y, dhv.y, c_AW[a], c_AH[a], acx1, acy, x1, y1, x2, y2);
        bool k2 = decode_clip(dx.z, dy.z, dwv.z, dhv.z, c_AW[a], c_AH[a], acx2, acy, x1, y1, x2, y2);
        bool k3 = decode_clip(dx.w, dy.w, dwv.w, dhv.w, c_AW[a], c_AH[a], acx3, acy, x1, y1, x2, y2);
        uint32_t key0 = f2key(k0 ? s.x : -1e30f);
        uint32_t key1 = f2key(k1 ? s.y : -1e30f);
        uint32_t key2 = f2key(k2 ? s.z : -1e30f);
        uint32_t key3 = f2key(k3 ? s.w : -1e30f);
        *(uint4*)&kb[a * NHW] = make_uint4(key0, key1, key2, key3);
        atomicAdd(&hist[key0 >> BIN_SHIFT], 1u);
        atomicAdd(&hist[key1 >> BIN_SHIFT], 1u);
        atomicAdd(&hist[key2 >> BIN_SHIFT], 1u);
        atomicAdd(&hist[key3 >> BIN_SHIFT], 1u);
    }
    __syncthreads();
    uint32_t* gh = ghist + ((size_t)b << 13);
    for (int i = threadIdx.x; i < BINS; i += 256) {
        uint32_t c = hist[i];
        if (c) atomicAdd(&gh[i], c);
    }
}

// ---------------- K2: find threshold bin; also zero cnt for k_compact ----------------
__global__ __launch_bounds__(256) void k_thresh(const uint32_t* __restrict__ ghist,
                                                uint32_t* __restrict__ thresh,
                                                uint32_t* __restrict__ cnt) {
    __shared__ uint32_t part[256];
    int b = blockIdx.x;
    const uint32_t* gh = ghist + ((size_t)b << 13);
    uint32_t p = 0;
    int base = threadIdx.x * 32;
    for (int k = 0; k < 32; ++k) p += gh[base + k];
    part[threadIdx.x] = p;
    __syncthreads();
    if (threadIdx.x == 0) {
        uint32_t cum = 0;
        int tb = 0;
        for (int c = 255; c >= 0; --c) {
            if (cum + part[c] >= (uint32_t)PRE) {
                for (int i = 31; i >= 0; --i) {
                    cum += gh[c * 32 + i];
                    if (cum >= (uint32_t)PRE) { tb = c * 32 + i; break; }
                }
                break;
            }
            cum += part[c];
        }
        thresh[b] = (uint32_t)tb << BIN_SHIFT;
        cnt[b] = 0;
    }
}

// ---------------- K3: compact from key array; LDS staging, 1 atomic/block ----------------
__global__ __launch_bounds__(256) void k_compact(const uint32_t* __restrict__ keys,
                                                 const uint32_t* __restrict__ thresh,
                                                 uint32_t* __restrict__ cnt,
                                                 uint64_t* __restrict__ cand) {
    __shared__ uint64_t stage[2304];
    __shared__ uint32_t sCount;
    __shared__ uint32_t sBase;
    if (threadIdx.x == 0) sCount = 0;
    __syncthreads();
    int bid = blockIdx.x;
    int b = bid >> 7;
    int hw = ((bid & 127) << 8) | threadIdx.x;
    int lane = threadIdx.x & 63;
    const uint32_t* kb = keys + (size_t)b * NANCH * NHW + hw;
    uint32_t th = thresh[b];
#pragma unroll
    for (int a = 0; a < NANCH; ++a) {
        uint32_t key = kb[a * NHW];
        bool valid = (key >= th);
        uint64_t mask = __ballot(valid);
        if (mask) {
            int leader = __ffsll((unsigned long long)mask) - 1;
            uint32_t wb = 0;
            if (lane == leader) wb = atomicAdd(&sCount, (uint32_t)__popcll(mask));
            wb = (uint32_t)__shfl((int)wb, leader);
            if (valid) {
                int rank = __popcll(mask & ((1ull << lane) - 1ull));
                uint32_t n = (uint32_t)(hw * NANCH + a);
                stage[wb + rank] = ((uint64_t)key << 32) | (uint32_t)(~n);
            }
        }
    }
    __syncthreads();
    if (threadIdx.x == 0) sBase = atomicAdd(&cnt[b], sCount);
    __syncthreads();
    uint32_t total = sCount, base = sBase;
    for (uint32_t i = threadIdx.x; i < total; i += 256) {
        uint32_t pos = base + i;
        if (pos < (uint32_t)CAPN) cand[(size_t)b * CAPN + pos] = stage[i];
    }
}

// ---------------- K4a: sort each 1024-chunk DESCENDING (local bitonic) ----------------
__global__ __launch_bounds__(512) void k_sortA(const uint32_t* __restrict__ cnt,
                                               uint64_t* __restrict__ cand) {
    __shared__ uint64_t sm[1024];
    int b = blockIdx.x >> 3, c = blockIdx.x & 7;
    uint32_t C = cnt[b];
    if (C > (uint32_t)CAPN) C = CAPN;
    uint64_t* cb = cand + (size_t)b * CAPN;
    int base = c << 10;
    for (int li = threadIdx.x; li < 1024; li += 512) {
        int gi = base + li;
        sm[li] = (gi < (int)C) ? cb[gi] : 0ull;
    }
    __syncthreads();
    for (int k = 2; k <= 1024; k <<= 1) {
        for (int j = k >> 1; j > 0; j >>= 1) {
            for (int li = threadIdx.x; li < 1024; li += 512) {
                int lxj = li ^ j;
                if (lxj > li) {
                    uint64_t va = sm[li], vb = sm[lxj];
                    bool up = ((li & k) == 0);
                    bool sw = up ? (va < vb) : (va > vb);
                    if (sw) { sm[li] = vb; sm[lxj] = va; }
                }
            }
            __syncthreads();
        }
    }
    for (int li = threadIdx.x; li < 1024; li += 512) cb[base + li] = sm[li];
}

// ---------------- K4b: fused 3-level merge-path in LDS -> fully sorted 8192 -------------
__device__ __forceinline__ uint64_t mp_elem(const uint64_t* __restrict__ sm, int p, int Rlog) {
    int R = 1 << Rlog;
    int pair = p >> (Rlog + 1);
    int q = p & ((R << 1) - 1);
    const uint64_t* A = sm + ((size_t)(pair << 1) << Rlog);
    const uint64_t* B = A + R;
    int lo = (q > R) ? (q - R) : 0;
    int hi = (q < R) ? q : R;
    while (lo < hi) {
        int mid = (lo + hi) >> 1;
        if (A[mid] > B[q - mid - 1]) lo = mid + 1; else hi = mid;
    }
    int i = lo, j = q - lo;
    uint64_t aV = (i < R) ? A[i] : 0ull;
    uint64_t bV = (j < R) ? B[j] : 0ull;
    return (aV > bV) ? aV : bV;
}

__global__ __launch_bounds__(1024) void k_merge2(uint64_t* __restrict__ cand) {
    __shared__ uint64_t sm[CAPN];            // 64 KiB
    int b = blockIdx.x;
    uint64_t* cb = cand + (size_t)b * CAPN;
    for (int i = threadIdx.x; i < CAPN; i += 1024) sm[i] = cb[i];
    __syncthreads();
#pragma unroll
    for (int lvl = 10; lvl <= 12; ++lvl) {
        uint64_t v0 = mp_elem(sm, threadIdx.x + 0 * 1024, lvl);
        uint64_t v1 = mp_elem(sm, threadIdx.x + 1 * 1024, lvl);
        uint64_t v2 = mp_elem(sm, threadIdx.x + 2 * 1024, lvl);
        uint64_t v3 = mp_elem(sm, threadIdx.x + 3 * 1024, lvl);
        uint64_t v4 = mp_elem(sm, threadIdx.x + 4 * 1024, lvl);
        uint64_t v5 = mp_elem(sm, threadIdx.x + 5 * 1024, lvl);
        uint64_t v6 = mp_elem(sm, threadIdx.x + 6 * 1024, lvl);
        uint64_t v7 = mp_elem(sm, threadIdx.x + 7 * 1024, lvl);
        __syncthreads();
        sm[threadIdx.x + 0 * 1024] = v0;
        sm[threadIdx.x + 1 * 1024] = v1;
        sm[threadIdx.x + 2 * 1024] = v2;
        sm[threadIdx.x + 3 * 1024] = v3;
        sm[threadIdx.x + 4 * 1024] = v4;
        sm[threadIdx.x + 5 * 1024] = v5;
        sm[threadIdx.x + 6 * 1024] = v6;
        sm[threadIdx.x + 7 * 1024] = v7;
        __syncthreads();
    }
    for (int i = threadIdx.x; i < CAPN; i += 1024) cb[i] = sm[i];
}

// ---------------- K4c: direct gather/decode (cand fully sorted desc) --------------------
__global__ __launch_bounds__(256) void k_gather(const uint64_t* __restrict__ cand,
                                                const float* __restrict__ lab,
                                                const float* __restrict__ reg,
                                                float4* __restrict__ boxes,
                                                float* __restrict__ scores) {
    int g = blockIdx.x * 256 + threadIdx.x;
    if (g >= NBATCH * PRE) return;
    int b = g / PRE, p = g - b * PRE;
    uint64_t v = cand[(size_t)b * CAPN + p];
    uint32_t n = ~(uint32_t)(v & 0xFFFFFFFFull);
    if (n >= (uint32_t)NTOT) n = 0;
    int a = (int)(n % NANCH);
    int hw = (int)(n / NANCH);
    int w = hw & 255, h = hw >> 8;
    const float* lb0 = lab + (size_t)b * 18 * NHW;
    const float* rb0 = reg + (size_t)b * 36 * NHW;
    float s  = lb0[(2 * a + 1) * NHW + hw];
    float dx = rb0[(4 * a + 0) * NHW + hw];
    float dy = rb0[(4 * a + 1) * NHW + hw];
    float dwv = rb0[(4 * a + 2) * NHW + hw];
    float dhv = rb0[(4 * a + 3) * NHW + hw];
    float acx = (float)(w * 16) + 7.5f;
    float acy = (float)(h * 16) + 7.5f;
    float x1, y1, x2, y2;
    decode_clip(dx, dy, dwv, dhv, c_AW[a], c_AH[a], acx, acy, x1, y1, x2, y2);
    boxes[b * PRE + p] = make_float4(x1, y1, x2, y2);
    scores[b * PRE + p] = s;
}

// ---------------- K6a: suppression bits, rows<384 x cols<384 ONLY (6 words/row) --------
__global__ __launch_bounds__(512) void k_iou(const float4* __restrict__ boxes,
                                             uint64_t* __restrict__ supp) {
    __shared__ float4 lb[RROWS];             // 6144 B
    __shared__ float  la[RROWS];             // 1536 B
    int blk = blockIdx.x % 48;               // 48 blocks per batch, 8 rows each
    int b   = blockIdx.x / 48;
    const float4* bb = boxes + b * PRE;
    for (int i = threadIdx.x; i < RROWS; i += 512) {
        float4 v = bb[i];
        lb[i] = v;
        la[i] = __fmul_rn(__fadd_rn(__fsub_rn(v.z, v.x), 1.f),
                          __fadd_rn(__fsub_rn(v.w, v.y), 1.f));
    }
    __syncthreads();
    int wave = threadIdx.x >> 6, lane = threadIdx.x & 63;
    int r = (blk << 3) + wave;               // [0, 384)
    float4 bi = lb[r];
    float ai = la[r];
    uint64_t* sr = supp + ((size_t)b * RROWS + r) * SWORDS;
#pragma unroll
    for (int w = 0; w < SWORDS; ++w) {
        int j = (w << 6) | lane;
        bool s = iou_sup(bi, ai, lb[j], la[j]);
        uint64_t m = __ballot(s);
        if (lane == 0) sr[w] = m;
    }
}

// ---------------- K6b: register-resident walk + fused output write ---------------------
// lane l holds words 0..5 of rows 64i+l (i=0..5): 36 uint64 = 72 VGPRs.
#define RD32(V, L) __builtin_amdgcn_readlane((uint32_t)(V), (L))
#define RDL64(V, L) ((uint64_t)(uint32_t)RD32((V), (L)) | \
                     ((uint64_t)(uint32_t)RD32((uint32_t)((V) >> 32), (L)) << 32))

#define LOADW(I) do {                                                           \
    const uint64_t* _rp = sbase + (size_t)(((I) << 6) + lane) * SWORDS;         \
    m##I##0 = _rp[0]; m##I##1 = _rp[1]; m##I##2 = _rp[2];                       \
    m##I##3 = _rp[3]; m##I##4 = _rp[4]; m##I##5 = _rp[5];                       \
} while (0)

#define WINDOW(I) {                                                             \
    uint64_t curw = s##I;                                                       \
    while (curw) {                                                              \
        int rl = __ffsll((unsigned long long)curw) - 1;                         \
        if (lane == 0) sidx[t] = (uint32_t)(((I) << 6) + rl);                   \
        ++t;                                                                    \
        s0 &= ~RDL64(m##I##0, rl); s1 &= ~RDL64(m##I##1, rl);                   \
        s2 &= ~RDL64(m##I##2, rl); s3 &= ~RDL64(m##I##3, rl);                   \
        s4 &= ~RDL64(m##I##4, rl); s5 &= ~RDL64(m##I##5, rl);                   \
        if (t >= POST) goto walk_done;                                          \
        curw = s##I;                                                            \
    }                                                                           \
}

__global__ __launch_bounds__(64, 1) void k_walk(const uint64_t* __restrict__ supp,
                                                const float4* __restrict__ boxes,
                                                const float* __restrict__ scores,
                                                uint32_t* __restrict__ flags,
                                                float* __restrict__ out) {
    __shared__ uint32_t sidx[POST];
    int b = blockIdx.x;
    int lane = threadIdx.x;
    const uint64_t* sbase = supp + (size_t)b * RROWS * SWORDS;
    uint64_t m00,m01,m02,m03,m04,m05;
    uint64_t m10,m11,m12,m13,m14,m15;
    uint64_t m20,m21,m22,m23,m24,m25;
    uint64_t m30,m31,m32,m33,m34,m35;
    uint64_t m40,m41,m42,m43,m44,m45;
    uint64_t m50,m51,m52,m53,m54,m55;
    LOADW(0); LOADW(1); LOADW(2); LOADW(3); LOADW(4); LOADW(5);
    uint64_t s0 = ~0ull, s1 = ~0ull, s2 = ~0ull, s3 = ~0ull, s4 = ~0ull, s5 = ~0ull;
    int t = 0;
    WINDOW(0)
    WINDOW(1)
    WINDOW(2)
    WINDOW(3)
    WINDOW(4)
    WINDOW(5)
    // low-384 columns exhausted before POST emissions -> rare exact serial fallback
    if (lane == 0) flags[b] = 1u;
    return;
walk_done:
    __syncthreads();                            // lane0's sidx writes visible to all lanes
    for (int tt = lane; tt < POST; tt += 64) {
        uint32_t i = sidx[tt];
        float4 bc = boxes[b * PRE + i];
        size_t ob = ((size_t)b * POST + tt) * 4;
        out[ob + 0] = bc.x; out[ob + 1] = bc.y;
        out[ob + 2] = bc.z; out[ob + 3] = bc.w;
        out[(size_t)NBATCH * POST * 4 + (size_t)b * POST + tt] = scores[b * PRE + i];
    }
    if (lane == 0) flags[b] = 0u;
}

// ---------------- K6c: rare exact fallback; from-scratch serial greedy + output --------
__global__ __launch_bounds__(512) void k_resume(const float4* __restrict__ boxes,
                                                const float* __restrict__ scores,
                                                const uint32_t* __restrict__ flags,
                                                float* __restrict__ out) {
    int b = blockIdx.x;
    if (flags[b] == 0) return;
    __shared__ uint64_t alive[NWORDS];
    __shared__ uint32_t sCur;
    int tid = threadIdx.x;
    const float4* bb = boxes + b * PRE;
    const float* sb = scores + b * PRE;
    if (tid < NWORDS) alive[tid] = (tid == NWORDS - 1) ? ((1ull << 48) - 1ull) : ~0ull;
    __syncthreads();
    for (int t = 0; t < POST; ++t) {
        if (tid == 0) sCur = 0xFFFFFFFFu;
        __syncthreads();
        if (tid < NWORDS) {
            uint64_t wd = alive[tid];
            if (wd) atomicMin(&sCur, (uint32_t)(tid * 64 + (__ffsll((unsigned long long)wd) - 1)));
        }
        __syncthreads();
        uint32_t cur = sCur;
        uint32_t e = (cur < (uint32_t)PRE) ? cur : 0u;
        float4 bc = bb[e];
        if (tid == 0) {
            size_t ob = ((size_t)b * POST + t) * 4;
            out[ob + 0] = bc.x; out[ob + 1] = bc.y;
            out[ob + 2] = bc.z; out[ob + 3] = bc.w;
            out[(size_t)NBATCH * POST * 4 + (size_t)b * POST + t] = sb[e];
            if (cur < (uint32_t)PRE)
                atomicAnd(&alive[cur >> 6], ~(1ull << (cur & 63)));
        }
        if (cur < (uint32_t)PRE) {
            float areaC = __fmul_rn(__fadd_rn(__fsub_rn(bc.z, bc.x), 1.f),
                                    __fadd_rn(__fsub_rn(bc.w, bc.y), 1.f));
            for (uint32_t j = cur + 1 + tid; j < (uint32_t)PRE; j += 512) {
                uint64_t wd = alive[j >> 6];
                if ((wd >> (j & 63)) & 1ull) {
                    float4 bj = bb[j];
                    float areaJ = __fmul_rn(__fadd_rn(__fsub_rn(bj.z, bj.x), 1.f),
                                            __fadd_rn(__fsub_rn(bj.w, bj.y), 1.f));
                    if (iou_sup(bc, areaC, bj, areaJ))
                        atomicAnd(&alive[j >> 6], ~(1ull << (j & 63)));
                }
            }
        }
        __syncthreads();
    }
}

extern "C" void kernel_launch(void* const* d_in, const int* in_sizes, int n_in,
                              void* d_out, int out_size, void* d_ws, size_t ws_size,
                              hipStream_t stream) {
    (void)in_sizes; (void)n_in; (void)out_size; (void)ws_size;
    const float* lab = (const float*)d_in[0];
    const float* reg = (const float*)d_in[1];
    float* out = (float*)d_out;
    char* ws = (char*)d_ws;

    // workspace layout (bytes)
    uint32_t* ghist  = (uint32_t*)(ws + 0);          // 524288
    uint32_t* cnt    = (uint32_t*)(ws + 524288);     // 64
    uint32_t* thr    = (uint32_t*)(ws + 524352);     // 64
    uint64_t* cand   = (uint64_t*)(ws + 524416);     // -> 1572992
    float4*   boxes  = (float4*)  (ws + 1572992);    // -> 3108992
    float*    scores = (float*)   (ws + 3108992);    // -> 3492992
    uint64_t* supp   = (uint64_t*)(ws + 3492992);    // 16*384*6*8 = 294912 -> 3787904
    uint32_t* flags  = (uint32_t*)(ws + 3787904);    // 64
    uint32_t* keys   = (uint32_t*)(ws + 3787968);    // -> 22662336

    k_zero   <<<128, 256, 0, stream>>>((uint4*)ghist);
    k_hist   <<<512, 256, 0, stream>>>(lab, reg, ghist, keys);
    k_thresh <<<NBATCH, 256, 0, stream>>>(ghist, thr, cnt);
    k_compact<<<2048, 256, 0, stream>>>(keys, thr, cnt, cand);
    k_sortA  <<<NBATCH * 8, 512, 0, stream>>>(cnt, cand);
    k_merge2 <<<NBATCH, 1024, 0, stream>>>(cand);
    k_gather <<<(NBATCH * PRE + 255) / 256, 256, 0, stream>>>(cand, lab, reg, boxes, scores);
    k_iou    <<<NBATCH * 48, 512, 0, stream>>>(boxes, supp);
    k_walk   <<<NBATCH, 64, 0, stream>>>(supp, boxes, scores, flags, out);
    k_resume <<<NBATCH, 512, 0, stream>>>(boxes, scores, flags, out);
}

// Round 26
// 150.615 us; speedup vs baseline: 1.0972x; 1.0972x over previous
//
#include <hip/hip_runtime.h>
#include <stdint.h>

#define NBATCH 16
#define NANCH  9
#define NHGT   128
#define NWID   256
#define NHW    (NHGT * NWID)       // 32768
#define NTOT   (NHW * NANCH)       // 294912
#define PRE    6000
#define POST   300
#define CAPN   8192
#define BINS   8192
#define BIN_SHIFT 19
#define NWORDS 94                  // ceil(6000/64)
#define RROWS  384                 // suppression-matrix rows+cols (exact fallback beyond)
#define SWORDS 6                   // stored words per row (columns < RROWS only)

// exact replacement for (div_rn(inter,uni) > 0.7f):  (double)inter >= (double)uni * M
#define MIDP 0x1.6666668p-1

__device__ __constant__ float c_AW[NANCH] = {184.f,368.f,736.f,128.f,256.f,512.f,88.f,176.f,352.f};
__device__ __constant__ float c_AH[NANCH] = {96.f,192.f,384.f,128.f,256.f,512.f,176.f,352.f,704.f};

__device__ __forceinline__ uint32_t f2key(float f) {
    uint32_t u = __float_as_uint(f);
    return (u & 0x80000000u) ? ~u : (u | 0x80000000u);
}

__device__ __forceinline__ bool iou_sup(const float4 bi, float areaI, const float4 bj, float areaJ) {
    float xx1 = fmaxf(bi.x, bj.x);
    float yy1 = fmaxf(bi.y, bj.y);
    float xx2 = fminf(bi.z, bj.z);
    float yy2 = fminf(bi.w, bj.w);
    float iw = fmaxf(__fadd_rn(__fsub_rn(xx2, xx1), 1.f), 0.f);
    float ih = fmaxf(__fadd_rn(__fsub_rn(yy2, yy1), 1.f), 0.f);
    float inter = __fmul_rn(iw, ih);
    float uni = __fsub_rn(__fadd_rn(areaI, areaJ), inter);
    return ((double)inter >= (double)uni * MIDP);
}

__device__ __forceinline__ bool decode_clip(float dx, float dy, float dw, float dh,
                                            float aw, float ah, float acx, float acy,
                                            float& x1, float& y1, float& x2, float& y2) {
    float pcx = __fadd_rn(__fmul_rn(dx, aw), acx);
    float pcy = __fadd_rn(__fmul_rn(dy, ah), acy);
    float pw  = __fmul_rn(expf(dw), aw);
    float ph  = __fmul_rn(expf(dh), ah);
    float hx  = __fmul_rn(0.5f, pw);
    float hy  = __fmul_rn(0.5f, ph);
    x1 = __fsub_rn(pcx, hx);
    y1 = __fsub_rn(pcy, hy);
    x2 = __fadd_rn(pcx, hx);
    y2 = __fadd_rn(pcy, hy);
    x1 = fminf(fmaxf(x1, 0.f), 4095.f);
    x2 = fminf(fmaxf(x2, 0.f), 4095.f);
    y1 = fminf(fmaxf(y1, 0.f), 2047.f);
    y2 = fminf(fmaxf(y2, 0.f), 2047.f);
    float wpl = __fadd_rn(__fsub_rn(x2, x1), 1.f);
    float hpl = __fadd_rn(__fsub_rn(y2, y1), 1.f);
    return (wpl >= 16.f) && (hpl >= 16.f);
}

// ---------------- K0: zero ghist ----------------
__global__ __launch_bounds__(256) void k_zero(uint4* __restrict__ ghist4) {
    ghist4[blockIdx.x * 256 + threadIdx.x] = make_uint4(0, 0, 0, 0);  // 524288 B
}

// ---------------- K1: LDS histogram (512 blocks, float4 loads) + key array ----------------
__global__ __launch_bounds__(256) void k_hist(const float* __restrict__ lab,
                                              const float* __restrict__ reg,
                                              uint32_t* __restrict__ ghist,
                                              uint32_t* __restrict__ keys) {
    __shared__ uint32_t hist[BINS];
    for (int i = threadIdx.x; i < BINS; i += 256) hist[i] = 0;
    __syncthreads();
    int b = blockIdx.x >> 5, sub = blockIdx.x & 31;
    int hw = (sub << 10) | (threadIdx.x << 2);
    int h = hw >> 8, w = hw & 255;
    const float* lb = lab + (size_t)b * 18 * NHW + hw;
    const float* rb = reg + (size_t)b * 36 * NHW + hw;
    uint32_t* kb = keys + (size_t)b * NANCH * NHW + hw;
    float acy  = (float)(h * 16) + 7.5f;
    float acx0 = (float)(w * 16) + 7.5f;
    float acx1 = acx0 + 16.0f;
    float acx2 = acx0 + 32.0f;
    float acx3 = acx0 + 48.0f;
#pragma unroll
    for (int a = 0; a < NANCH; ++a) {
        float4 s  = *(const float4*)&lb[(2 * a + 1) * NHW];
        float4 dx = *(const float4*)&rb[(4 * a + 0) * NHW];
        float4 dy = *(const float4*)&rb[(4 * a + 1) * NHW];
        float4 dwv = *(const float4*)&rb[(4 * a + 2) * NHW];
        float4 dhv = *(const float4*)&rb[(4 * a + 3) * NHW];
        float x1, y1, x2, y2;
        bool k0 = decode_clip(dx.x, dy.x, dwv.x, dhv.x, c_AW[a], c_AH[a], acx0, acy, x1, y1, x2, y2);
        bool k1 = decode_clip(dx.y, dy.y, dwv.y, dhv.y, c_AW[a], c_AH[a], acx1, acy, x1, y1, x2, y2);
        bool k2 = decode_clip(dx.z, dy.z, dwv.z, dhv.z, c_AW[a], c_AH[a], acx2, acy, x1, y1, x2, y2);
        bool k3 = decode_clip(dx.w, dy.w, dwv.w, dhv.w, c_AW[a], c_AH[a], acx3, acy, x1, y1, x2, y2);
        uint32_t key0 = f2key(k0 ? s.x : -1e30f);
        uint32_t key1 = f2key(k1 ? s.y : -1e30f);
        uint32_t key2 = f2key(k2 ? s.z : -1e30f);
        uint32_t key3 = f2key(k3 ? s.w : -1e30f);
        *(uint4*)&kb[a * NHW] = make_uint4(key0, key1, key2, key3);
        atomicAdd(&hist[key0 >> BIN_SHIFT], 1u);
        atomicAdd(&hist[key1 >> BIN_SHIFT], 1u);
        atomicAdd(&hist[key2 >> BIN_SHIFT], 1u);
        atomicAdd(&hist[key3 >> BIN_SHIFT], 1u);
    }
    __syncthreads();
    uint32_t* gh = ghist + ((size_t)b << 13);
    for (int i = threadIdx.x; i < BINS; i += 256) {
        uint32_t c = hist[i];
        if (c) atomicAdd(&gh[i], c);
    }
}

// ---------------- K2: find threshold bin; also zero cnt for k_compact ----------------
__global__ __launch_bounds__(256) void k_thresh(const uint32_t* __restrict__ ghist,
                                                uint32_t* __restrict__ thresh,
                                                uint32_t* __restrict__ cnt) {
    __shared__ uint32_t part[256];
    int b = blockIdx.x;
    const uint32_t* gh = ghist + ((size_t)b << 13);
    uint32_t p = 0;
    int base = threadIdx.x * 32;
    for (int k = 0; k < 32; ++k) p += gh[base + k];
    part[threadIdx.x] = p;
    __syncthreads();
    if (threadIdx.x == 0) {
        uint32_t cum = 0;
        int tb = 0;
        for (int c = 255; c >= 0; --c) {
            if (cum + part[c] >= (uint32_t)PRE) {
                for (int i = 31; i >= 0; --i) {
                    cum += gh[c * 32 + i];
                    if (cum >= (uint32_t)PRE) { tb = c * 32 + i; break; }
                }
                break;
            }
            cum += part[c];
        }
        thresh[b] = (uint32_t)tb << BIN_SHIFT;
        cnt[b] = 0;
    }
}

// ---------------- K3: compact from key array; LDS staging, 1 atomic/block ----------------
__global__ __launch_bounds__(256) void k_compact(const uint32_t* __restrict__ keys,
                                                 const uint32_t* __restrict__ thresh,
                                                 uint32_t* __restrict__ cnt,
                                                 uint64_t* __restrict__ cand) {
    __shared__ uint64_t stage[2304];
    __shared__ uint32_t sCount;
    __shared__ uint32_t sBase;
    if (threadIdx.x == 0) sCount = 0;
    __syncthreads();
    int bid = blockIdx.x;
    int b = bid >> 7;
    int hw = ((bid & 127) << 8) | threadIdx.x;
    int lane = threadIdx.x & 63;
    const uint32_t* kb = keys + (size_t)b * NANCH * NHW + hw;
    uint32_t th = thresh[b];
#pragma unroll
    for (int a = 0; a < NANCH; ++a) {
        uint32_t key = kb[a * NHW];
        bool valid = (key >= th);
        uint64_t mask = __ballot(valid);
        if (mask) {
            int leader = __ffsll((unsigned long long)mask) - 1;
            uint32_t wb = 0;
            if (lane == leader) wb = atomicAdd(&sCount, (uint32_t)__popcll(mask));
            wb = (uint32_t)__shfl((int)wb, leader);
            if (valid) {
                int rank = __popcll(mask & ((1ull << lane) - 1ull));
                uint32_t n = (uint32_t)(hw * NANCH + a);
                stage[wb + rank] = ((uint64_t)key << 32) | (uint32_t)(~n);
            }
        }
    }
    __syncthreads();
    if (threadIdx.x == 0) sBase = atomicAdd(&cnt[b], sCount);
    __syncthreads();
    uint32_t total = sCount, base = sBase;
    for (uint32_t i = threadIdx.x; i < total; i += 256) {
        uint32_t pos = base + i;
        if (pos < (uint32_t)CAPN) cand[(size_t)b * CAPN + pos] = stage[i];
    }
}

// ---------------- K4a: sort each 1024-chunk DESCENDING (local bitonic) ----------------
__global__ __launch_bounds__(512) void k_sortA(const uint32_t* __restrict__ cnt,
                                               uint64_t* __restrict__ cand) {
    __shared__ uint64_t sm[1024];
    int b = blockIdx.x >> 3, c = blockIdx.x & 7;
    uint32_t C = cnt[b];
    if (C > (uint32_t)CAPN) C = CAPN;
    uint64_t* cb = cand + (size_t)b * CAPN;
    int base = c << 10;
    for (int li = threadIdx.x; li < 1024; li += 512) {
        int gi = base + li;
        sm[li] = (gi < (int)C) ? cb[gi] : 0ull;
    }
    __syncthreads();
    for (int k = 2; k <= 1024; k <<= 1) {
        for (int j = k >> 1; j > 0; j >>= 1) {
            for (int li = threadIdx.x; li < 1024; li += 512) {
                int lxj = li ^ j;
                if (lxj > li) {
                    uint64_t va = sm[li], vb = sm[lxj];
                    bool up = ((li & k) == 0);
                    bool sw = up ? (va < vb) : (va > vb);
                    if (sw) { sm[li] = vb; sm[lxj] = va; }
                }
            }
            __syncthreads();
        }
    }
    for (int li = threadIdx.x; li < 1024; li += 512) cb[base + li] = sm[li];
}

// ---------------- K4b: pairwise merge-path (desc runs of length R=1<<Rlog) --------------
__global__ __launch_bounds__(256) void k_merge(const uint64_t* __restrict__ src,
                                               uint64_t* __restrict__ dst,
                                               int Rlog) {
    int g = blockIdx.x * 256 + threadIdx.x;
    if (g >= NBATCH * CAPN) return;
    int b = g >> 13;
    int p = g & (CAPN - 1);
    int R = 1 << Rlog;
    int pair = p >> (Rlog + 1);
    int q = p & ((R << 1) - 1);
    const uint64_t* A = src + (size_t)b * CAPN + ((size_t)(pair << 1) << Rlog);
    const uint64_t* B = A + R;
    int lo = (q > R) ? (q - R) : 0;
    int hi = (q < R) ? q : R;
    while (lo < hi) {
        int mid = (lo + hi) >> 1;
        if (A[mid] > B[q - mid - 1]) lo = mid + 1; else hi = mid;
    }
    int i = lo, j = q - lo;
    uint64_t aV = (i < R) ? A[i] : 0ull;
    uint64_t bV = (j < R) ? B[j] : 0ull;
    dst[(size_t)b * CAPN + p] = (aV > bV) ? aV : bV;
}

// ---------------- K4c: merge-path top-PRE over two DESC 4096-runs + gather/decode -------
__global__ __launch_bounds__(256) void k_mergegather(const uint64_t* __restrict__ cand,
                                                     const float* __restrict__ lab,
                                                     const float* __restrict__ reg,
                                                     float4* __restrict__ boxes,
                                                     float* __restrict__ scores) {
    int g = blockIdx.x * 256 + threadIdx.x;
    if (g >= NBATCH * PRE) return;
    int b = g / PRE, p = g - b * PRE;
    const uint64_t* A = cand + (size_t)b * CAPN;
    const uint64_t* B = A + 4096;
    int lo = (p > 4096) ? (p - 4096) : 0;
    int hi = (p < 4096) ? p : 4096;
    while (lo < hi) {
        int mid = (lo + hi) >> 1;
        if (A[mid] > B[p - mid - 1]) lo = mid + 1; else hi = mid;
    }
    int i = lo, j = p - lo;
    uint64_t aV = (i < 4096) ? A[i] : 0ull;
    uint64_t bV = (j < 4096) ? B[j] : 0ull;
    uint64_t v = (aV > bV) ? aV : bV;
    uint32_t n = ~(uint32_t)(v & 0xFFFFFFFFull);
    if (n >= (uint32_t)NTOT) n = 0;
    int a = (int)(n % NANCH);
    int hw = (int)(n / NANCH);
    int w = hw & 255, h = hw >> 8;
    const float* lb0 = lab + (size_t)b * 18 * NHW;
    const float* rb0 = reg + (size_t)b * 36 * NHW;
    float s  = lb0[(2 * a + 1) * NHW + hw];
    float dx = rb0[(4 * a + 0) * NHW + hw];
    float dy = rb0[(4 * a + 1) * NHW + hw];
    float dwv = rb0[(4 * a + 2) * NHW + hw];
    float dhv = rb0[(4 * a + 3) * NHW + hw];
    float acx = (float)(w * 16) + 7.5f;
    float acy = (float)(h * 16) + 7.5f;
    float x1, y1, x2, y2;
    decode_clip(dx, dy, dwv, dhv, c_AW[a], c_AH[a], acx, acy, x1, y1, x2, y2);
    boxes[b * PRE + p] = make_float4(x1, y1, x2, y2);
    scores[b * PRE + p] = s;
}

// ---------------- K6a: suppression bits, rows<384 x cols<384 ONLY (6 words/row) --------
__global__ __launch_bounds__(512) void k_iou(const float4* __restrict__ boxes,
                                             uint64_t* __restrict__ supp) {
    __shared__ float4 lb[RROWS];             // 6144 B
    __shared__ float  la[RROWS];             // 1536 B
    int blk = blockIdx.x % 48;               // 48 blocks per batch, 8 rows each
    int b   = blockIdx.x / 48;
    const float4* bb = boxes + b * PRE;
    for (int i = threadIdx.x; i < RROWS; i += 512) {
        float4 v = bb[i];
        lb[i] = v;
        la[i] = __fmul_rn(__fadd_rn(__fsub_rn(v.z, v.x), 1.f),
                          __fadd_rn(__fsub_rn(v.w, v.y), 1.f));
    }
    __syncthreads();
    int wave = threadIdx.x >> 6, lane = threadIdx.x & 63;
    int r = (blk << 3) + wave;               // [0, 384)
    float4 bi = lb[r];
    float ai = la[r];
    uint64_t* sr = supp + ((size_t)b * RROWS + r) * SWORDS;
#pragma unroll
    for (int w = 0; w < SWORDS; ++w) {
        int j = (w << 6) | lane;
        bool s = iou_sup(bi, ai, lb[j], la[j]);
        uint64_t m = __ballot(s);
        if (lane == 0) sr[w] = m;
    }
}

// ---------------- K6b: register-resident walk + fused output write ---------------------
// lane l holds words 0..5 of rows 64i+l (i=0..5): 36 uint64 = 72 VGPRs.
#define RD32(V, L) __builtin_amdgcn_readlane((uint32_t)(V), (L))
#define RDL64(V, L) ((uint64_t)(uint32_t)RD32((V), (L)) | \
                     ((uint64_t)(uint32_t)RD32((uint32_t)((V) >> 32), (L)) << 32))

#define LOADW(I) do {                                                           \
    const uint64_t* _rp = sbase + (size_t)(((I) << 6) + lane) * SWORDS;         \
    m##I##0 = _rp[0]; m##I##1 = _rp[1]; m##I##2 = _rp[2];                       \
    m##I##3 = _rp[3]; m##I##4 = _rp[4]; m##I##5 = _rp[5];                       \
} while (0)

#define WINDOW(I) {                                                             \
    uint64_t curw = s##I;                                                       \
    while (curw) {                                                              \
        int rl = __ffsll((unsigned long long)curw) - 1;                         \
        if (lane == 0) sidx[t] = (uint32_t)(((I) << 6) + rl);                   \
        ++t;                                                                    \
        s0 &= ~RDL64(m##I##0, rl); s1 &= ~RDL64(m##I##1, rl);                   \
        s2 &= ~RDL64(m##I##2, rl); s3 &= ~RDL64(m##I##3, rl);                   \
        s4 &= ~RDL64(m##I##4, rl); s5 &= ~RDL64(m##I##5, rl);                   \
        if (t >= POST) goto walk_done;                                          \
        curw = s##I;                                                            \
    }                                                                           \
}

__global__ __launch_bounds__(64, 1) void k_walk(const uint64_t* __restrict__ supp,
                                                const float4* __restrict__ boxes,
                                                const float* __restrict__ scores,
                                                uint32_t* __restrict__ flags,
                                                float* __restrict__ out) {
    __shared__ uint32_t sidx[POST];
    int b = blockIdx.x;
    int lane = threadIdx.x;
    const uint64_t* sbase = supp + (size_t)b * RROWS * SWORDS;
    uint64_t m00,m01,m02,m03,m04,m05;
    uint64_t m10,m11,m12,m13,m14,m15;
    uint64_t m20,m21,m22,m23,m24,m25;
    uint64_t m30,m31,m32,m33,m34,m35;
    uint64_t m40,m41,m42,m43,m44,m45;
    uint64_t m50,m51,m52,m53,m54,m55;
    LOADW(0); LOADW(1); LOADW(2); LOADW(3); LOADW(4); LOADW(5);
    uint64_t s0 = ~0ull, s1 = ~0ull, s2 = ~0ull, s3 = ~0ull, s4 = ~0ull, s5 = ~0ull;
    int t = 0;
    WINDOW(0)
    WINDOW(1)
    WINDOW(2)
    WINDOW(3)
    WINDOW(4)
    WINDOW(5)
    // low-384 columns exhausted before POST emissions -> rare exact serial fallback
    if (lane == 0) flags[b] = 1u;
    return;
walk_done:
    __syncthreads();                            // lane0's sidx writes visible to all lanes
    for (int tt = lane; tt < POST; tt += 64) {
        uint32_t i = sidx[tt];
        float4 bc = boxes[b * PRE + i];
        size_t ob = ((size_t)b * POST + tt) * 4;
        out[ob + 0] = bc.x; out[ob + 1] = bc.y;
        out[ob + 2] = bc.z; out[ob + 3] = bc.w;
        out[(size_t)NBATCH * POST * 4 + (size_t)b * POST + tt] = scores[b * PRE + i];
    }
    if (lane == 0) flags[b] = 0u;
}

// ---------------- K6c: rare exact fallback; from-scratch serial greedy + output --------
__global__ __launch_bounds__(512) void k_resume(const float4* __restrict__ boxes,
                                                const float* __restrict__ scores,
                                                const uint32_t* __restrict__ flags,
                                                float* __restrict__ out) {
    int b = blockIdx.x;
    if (flags[b] == 0) return;
    __shared__ uint64_t alive[NWORDS];
    __shared__ uint32_t sCur;
    int tid = threadIdx.x;
    const float4* bb = boxes + b * PRE;
    const float* sb = scores + b * PRE;
    if (tid < NWORDS) alive[tid] = (tid == NWORDS - 1) ? ((1ull << 48) - 1ull) : ~0ull;
    __syncthreads();
    for (int t = 0; t < POST; ++t) {
        if (tid == 0) sCur = 0xFFFFFFFFu;
        __syncthreads();
        if (tid < NWORDS) {
            uint64_t wd = alive[tid];
            if (wd) atomicMin(&sCur, (uint32_t)(tid * 64 + (__ffsll((unsigned long long)wd) - 1)));
        }
        __syncthreads();
        uint32_t cur = sCur;
        uint32_t e = (cur < (uint32_t)PRE) ? cur : 0u;
        float4 bc = bb[e];
        if (tid == 0) {
            size_t ob = ((size_t)b * POST + t) * 4;
            out[ob + 0] = bc.x; out[ob + 1] = bc.y;
            out[ob + 2] = bc.z; out[ob + 3] = bc.w;
            out[(size_t)NBATCH * POST * 4 + (size_t)b * POST + t] = sb[e];
            if (cur < (uint32_t)PRE)
                atomicAnd(&alive[cur >> 6], ~(1ull << (cur & 63)));
        }
        if (cur < (uint32_t)PRE) {
            float areaC = __fmul_rn(__fadd_rn(__fsub_rn(bc.z, bc.x), 1.f),
                                    __fadd_rn(__fsub_rn(bc.w, bc.y), 1.f));
            for (uint32_t j = cur + 1 + tid; j < (uint32_t)PRE; j += 512) {
                uint64_t wd = alive[j >> 6];
                if ((wd >> (j & 63)) & 1ull) {
                    float4 bj = bb[j];
                    float areaJ = __fmul_rn(__fadd_rn(__fsub_rn(bj.z, bj.x), 1.f),
                                            __fadd_rn(__fsub_rn(bj.w, bj.y), 1.f));
                    if (iou_sup(bc, areaC, bj, areaJ))
                        atomicAnd(&alive[j >> 6], ~(1ull << (j & 63)));
                }
            }
        }
        __syncthreads();
    }
}

extern "C" void kernel_launch(void* const* d_in, const int* in_sizes, int n_in,
                              void* d_out, int out_size, void* d_ws, size_t ws_size,
                              hipStream_t stream) {
    (void)in_sizes; (void)n_in; (void)out_size; (void)ws_size;
    const float* lab = (const float*)d_in[0];
    const float* reg = (const float*)d_in[1];
    float* out = (float*)d_out;
    char* ws = (char*)d_ws;

    // workspace layout (bytes)
    uint32_t* ghist  = (uint32_t*)(ws + 0);          // 524288
    uint32_t* cnt    = (uint32_t*)(ws + 524288);     // 64
    uint32_t* thr    = (uint32_t*)(ws + 524352);     // 64
    uint64_t* cand   = (uint64_t*)(ws + 524416);     // -> 1572992
    float4*   boxes  = (float4*)  (ws + 1572992);    // -> 3108992
    float*    scores = (float*)   (ws + 3108992);    // -> 3492992
    uint64_t* supp   = (uint64_t*)(ws + 3492992);    // 294912 -> 3787904
    uint32_t* flags  = (uint32_t*)(ws + 3787904);    // 64
    uint32_t* keys   = (uint32_t*)(ws + 3787968);    // -> 22662336
    uint64_t* cand2  = (uint64_t*)(ws + 22662336);   // -> 23710912

    k_zero       <<<128, 256, 0, stream>>>((uint4*)ghist);
    k_hist       <<<512, 256, 0, stream>>>(lab, reg, ghist, keys);
    k_thresh     <<<NBATCH, 256, 0, stream>>>(ghist, thr, cnt);
    k_compact    <<<2048, 256, 0, stream>>>(keys, thr, cnt, cand);
    k_sortA      <<<NBATCH * 8, 512, 0, stream>>>(cnt, cand);
    k_merge      <<<NBATCH * CAPN / 256, 256, 0, stream>>>(cand, cand2, 10);  // 1024 -> 2048
    k_merge      <<<NBATCH * CAPN / 256, 256, 0, stream>>>(cand2, cand, 11);  // 2048 -> 4096
    k_mergegather<<<(NBATCH * PRE + 255) / 256, 256, 0, stream>>>(cand, lab, reg, boxes, scores);
    k_iou        <<<NBATCH * 48, 512, 0, stream>>>(boxes, supp);
    k_walk       <<<NBATCH, 64, 0, stream>>>(supp, boxes, scores, flags, out);
    k_resume     <<<NBATCH, 512, 0, stream>>>(boxes, scores, flags, out);
}